// Round 5
// baseline (259.077 us; speedup 1.0000x reference)
//
#include <hip/hip_runtime.h>
#include <hip/hip_bf16.h>

#define D_MODEL 1024
#define NH 16
#define HD 64
#define BATCH 2
#define SEQ 2048
#define M_TOTAL (BATCH*SEQ)   // 4096

typedef _Float16 f16;
typedef _Float16 half8 __attribute__((ext_vector_type(8)));
typedef _Float16 half4v __attribute__((ext_vector_type(4)));
typedef float floatx4 __attribute__((ext_vector_type(4)));

__device__ inline void gload_lds16(const void* g, void* l) {
    __builtin_amdgcn_global_load_lds(
        (const __attribute__((address_space(1))) unsigned int*)g,
        (__attribute__((address_space(3))) unsigned int*)l, 16, 0, 0);
}

// ---------------- fp32 -> fp16 cast ----------------
__global__ void cvt_f32_f16(const float* __restrict__ src, f16* __restrict__ dst, int n4) {
    int i = blockIdx.x * blockDim.x + threadIdx.x;
    if (i < n4) {
        float4 v = ((const float4*)src)[i];
        half4v o = { (f16)v.x, (f16)v.y, (f16)v.z, (f16)v.w };
        *(half4v*)(dst + (long)i * 4) = o;
    }
}

// ---------------- E = exp(mask) in f16 ----------------
__global__ void exp_cvt(const float* __restrict__ src, f16* __restrict__ dst, int n4) {
    int i = blockIdx.x * blockDim.x + threadIdx.x;
    if (i < n4) {
        float4 v = ((const float4*)src)[i];
        half4v o = { (f16)__expf(v.x), (f16)__expf(v.y), (f16)__expf(v.z), (f16)__expf(v.w) };
        *(half4v*)(dst + (long)i * 4) = o;
    }
}

// ---------------- fp32 [R][C] -> fp16 [C][R] transpose-cast ----------------
__global__ void transpose_cvt(const float* __restrict__ src, f16* __restrict__ dst, int R, int C) {
    __shared__ float tile[32][33];
    int tx = threadIdx.x;
    int ty = threadIdx.y;
    int c0 = blockIdx.x * 32;
    int r0 = blockIdx.y * 32;
    for (int yy = 0; yy < 32; yy += 8)
        tile[ty + yy][tx] = src[(long)(r0 + ty + yy) * C + c0 + tx];
    __syncthreads();
    for (int yy = 0; yy < 32; yy += 8)
        dst[(long)(c0 + ty + yy) * R + r0 + tx] = (f16)tile[tx][ty + yy];
}

// ---------------- 128xTN-tile fp16 MFMA GEMM, BK=64, XOR-swizzled LDS ----------------
// MODE 0 (TN=128): scatter -> Qh [bh][s][d] (x0.125), Kh [bh][s][d], Vtg [bh][d][s]
// MODE 1 (TN=64):  out[m][n] = acc + bias (fp32)
template<int MODE, int TN>
__global__ __launch_bounds__(256) void gemm_mfma(
    const f16* __restrict__ A, const f16* __restrict__ BT,
    const float* __restrict__ bias,
    f16* __restrict__ Qh, f16* __restrict__ Kh, f16* __restrict__ Vtg,
    float* __restrict__ out, int Kdim)
{
    constexpr int NF = TN / 32;
    __shared__ f16 Ah[128 * 64];
    __shared__ f16 Bh[TN * 64];
    int tid  = threadIdx.x;
    int wid  = tid >> 6;
    int lane = tid & 63;
    int quad = lane >> 4;
    int l16  = lane & 15;
    int m0 = blockIdx.y * 128;
    int n0 = blockIdx.x * TN;
    int mrow = (wid >> 1) * 64;
    int ncol = (wid & 1) * (TN / 2);
    int grow = lane >> 3;
    int gchunk = (lane & 7) ^ (grow & 7);
    int sw0 = ((quad)     ^ (l16 & 7)) * 8;
    int sw1 = ((quad + 4) ^ (l16 & 7)) * 8;

    floatx4 acc[4][NF];
    #pragma unroll
    for (int mb = 0; mb < 4; mb++)
        #pragma unroll
        for (int nb = 0; nb < NF; nb++) acc[mb][nb] = (floatx4){0.f, 0.f, 0.f, 0.f};

    const f16* Abase = A + (long)m0 * Kdim;
    const f16* Bbase = BT + (long)n0 * Kdim;

    for (int k0 = 0; k0 < Kdim; k0 += 64) {
        #pragma unroll
        for (int j = 0; j < 4; j++) {
            int r = j * 32 + wid * 8 + grow;
            gload_lds16(Abase + (long)r * Kdim + k0 + gchunk * 8, &Ah[(j * 32 + wid * 8) * 64]);
        }
        #pragma unroll
        for (int j = 0; j < TN / 32; j++) {
            int r = j * 32 + wid * 8 + grow;
            gload_lds16(Bbase + (long)r * Kdim + k0 + gchunk * 8, &Bh[(j * 32 + wid * 8) * 64]);
        }
        __syncthreads();
        #pragma unroll
        for (int h = 0; h < 2; h++) {
            int sw = h ? sw1 : sw0;
            half8 af[4];
            #pragma unroll
            for (int mb = 0; mb < 4; mb++)
                af[mb] = *(const half8*)&Ah[(mrow + mb * 16 + l16) * 64 + sw];
            #pragma unroll
            for (int nb = 0; nb < NF; nb++) {
                half8 bf = *(const half8*)&Bh[(ncol + nb * 16 + l16) * 64 + sw];
                #pragma unroll
                for (int mb = 0; mb < 4; mb++)
                    acc[mb][nb] = __builtin_amdgcn_mfma_f32_16x16x32_f16(af[mb], bf, acc[mb][nb], 0, 0, 0);
            }
        }
        __syncthreads();
    }

    #pragma unroll
    for (int nb = 0; nb < NF; nb++) {
        int n = n0 + ncol + nb * 16 + l16;
        float bv = bias[n];
        int head = 0, t = 0, d = 0;
        if (MODE == 0) { head = n / 192; int rem = n % 192; t = rem / 64; d = rem % 64; }
        #pragma unroll
        for (int mb = 0; mb < 4; mb++) {
            int mbase = m0 + mrow + mb * 16 + quad * 4;
            if (MODE == 0) {
                int b = mbase >> 11;
                int s = mbase & 2047;
                long bh = b * NH + head;
                if (t == 2) {
                    half4v pack;
                    #pragma unroll
                    for (int r = 0; r < 4; r++) pack[r] = (f16)(acc[mb][nb][r] + bv);
                    *(half4v*)&Vtg[(bh * HD + d) * SEQ + s] = pack;
                } else if (t == 0) {
                    #pragma unroll
                    for (int r = 0; r < 4; r++)
                        Qh[(bh * SEQ + s + r) * HD + d] = (f16)((acc[mb][nb][r] + bv) * 0.125f);
                } else {
                    #pragma unroll
                    for (int r = 0; r < 4; r++)
                        Kh[(bh * SEQ + s + r) * HD + d] = (f16)(acc[mb][nb][r] + bv);
                }
            } else {
                #pragma unroll
                for (int r = 0; r < 4; r++)
                    out[(long)(mbase + r) * D_MODEL + n] = acc[mb][nb][r] + bv;
            }
        }
    }
}

// ---------------- flash attention v5 ----------------
// grid (SEQ/128, B*H), 256 threads (4 waves x 32 q-rows). Double-buffered K/V
// (ONE barrier/iter; DMA for tile i+1 flies during compute of tile i).
// S^T = K.Q^T MFMA -> lane holds 4 contiguous keys; p = E[q][k]*exp(qk/8) written
// as b64 into XOR-swizzled stride-64 Pl; softmax denom via ones-column MFMA.
__global__ __launch_bounds__(256) void attn(
    const f16* __restrict__ Qh, const f16* __restrict__ Kh, const f16* __restrict__ Vtg,
    const f16* __restrict__ E, f16* __restrict__ valh)
{
    __shared__ f16 Kl[2][64 * 64];
    __shared__ f16 Vt[2][64 * 64];
    __shared__ f16 Pl[4][32 * 64];
    int tid  = threadIdx.x;
    int wid  = tid >> 6;
    int lane = tid & 63;
    int quad = lane >> 4;
    int l16  = lane & 15;
    int bh = blockIdx.y;
    int b  = bh >> 4;
    int h  = bh & 15;
    int q0 = blockIdx.x * 128 + wid * 32;

    int grow = lane >> 3;            // 0..7
    int gpos = lane & 7;
    int sw0 = ((quad)     ^ (l16 & 7)) * 8;
    int sw1 = ((quad + 4) ^ (l16 & 7)) * 8;

    const f16* Qbase = Qh + ((long)bh * SEQ + q0) * HD;
    half8 qf[2][2];
    #pragma unroll
    for (int m = 0; m < 2; m++)
        #pragma unroll
        for (int c = 0; c < 2; c++)
            qf[m][c] = *(const half8*)&Qbase[(long)(m * 16 + l16) * HD + c * 32 + quad * 8];

    half8 vones;
    #pragma unroll
    for (int j = 0; j < 8; j++) vones[j] = (f16)1.0f;

    floatx4 Of[2][4];
    floatx4 Ofs[2];
    #pragma unroll
    for (int m = 0; m < 2; m++) {
        Ofs[m] = (floatx4){0.f, 0.f, 0.f, 0.f};
        #pragma unroll
        for (int nb = 0; nb < 4; nb++) Of[m][nb] = (floatx4){0.f, 0.f, 0.f, 0.f};
    }

    const f16* Kb = Kh + (long)bh * SEQ * HD;
    const f16* Vb = Vtg + (long)bh * HD * SEQ;

    // stage tile 0 into buffer 0
    #pragma unroll
    for (int j = 0; j < 2; j++) {
        int rb = j * 32 + wid * 8;
        int row = rb + grow;
        int gk = gpos ^ (row & 7);
        gload_lds16(Kb + (long)row * HD + gk * 8, &Kl[0][rb * 64]);
        gload_lds16(Vb + (long)row * SEQ + gk * 8, &Vt[0][rb * 64]);
    }

    for (int it = 0; it < SEQ / 64; it++) {
        int cur = it & 1;
        int k0 = it * 64;
        __syncthreads();   // drains DMA for tile `it`; all waves done reading buf cur^1

        if (it < SEQ / 64 - 1) {
            int kn = k0 + 64;
            #pragma unroll
            for (int j = 0; j < 2; j++) {
                int rb = j * 32 + wid * 8;
                int row = rb + grow;
                int gk = gpos ^ (row & 7);
                gload_lds16(Kb + (long)(kn + row) * HD + gk * 8, &Kl[cur ^ 1][rb * 64]);
                gload_lds16(Vb + (long)row * SEQ + kn + gk * 8, &Vt[cur ^ 1][rb * 64]);
            }
        }

        // E tile: contiguous half4 loads (lane's 4 keys are adjacent under S^T)
        half4v ef[2][4];
        #pragma unroll
        for (int m = 0; m < 2; m++)
            #pragma unroll
            for (int kb = 0; kb < 4; kb++)
                ef[m][kb] = *(const half4v*)&E[(long)(q0 + m * 16 + l16) * SEQ + k0 + kb * 16 + quad * 4];

        #pragma unroll
        for (int kb = 0; kb < 4; kb++) {
            half8 kf0 = *(const half8*)&Kl[cur][(kb * 16 + l16) * 64 + sw0];
            half8 kf1 = *(const half8*)&Kl[cur][(kb * 16 + l16) * 64 + sw1];
            #pragma unroll
            for (int m = 0; m < 2; m++) {
                floatx4 s = (floatx4){0.f, 0.f, 0.f, 0.f};
                s = __builtin_amdgcn_mfma_f32_16x16x32_f16(kf0, qf[m][0], s, 0, 0, 0);
                s = __builtin_amdgcn_mfma_f32_16x16x32_f16(kf1, qf[m][1], s, 0, 0, 0);
                // lane holds S[key=kb*16+quad*4+r][q=m*16+l16]
                half4v ph;
                #pragma unroll
                for (int r = 0; r < 4; r++)
                    ph[r] = (f16)((float)ef[m][kb][r] * __expf(s[r]));
                int c8 = ((kb * 2 + (quad >> 1)) ^ (l16 & 7)) * 8 + (quad & 1) * 4;
                *(half4v*)&Pl[wid][(m * 16 + l16) * 64 + c8] = ph;
            }
        }

        // wave-private LDS round-trip (C-layout -> A-layout); no barrier needed
        half8 pf[2][2];
        #pragma unroll
        for (int m = 0; m < 2; m++)
            #pragma unroll
            for (int c = 0; c < 2; c++) {
                int c8 = ((c * 4 + quad) ^ (l16 & 7)) * 8;
                pf[m][c] = *(const half8*)&Pl[wid][(m * 16 + l16) * 64 + c8];
            }

        #pragma unroll
        for (int nb = 0; nb < 4; nb++) {
            half8 vf0 = *(const half8*)&Vt[cur][(nb * 16 + l16) * 64 + sw0];
            half8 vf1 = *(const half8*)&Vt[cur][(nb * 16 + l16) * 64 + sw1];
            #pragma unroll
            for (int m = 0; m < 2; m++) {
                Of[m][nb] = __builtin_amdgcn_mfma_f32_16x16x32_f16(pf[m][0], vf0, Of[m][nb], 0, 0, 0);
                Of[m][nb] = __builtin_amdgcn_mfma_f32_16x16x32_f16(pf[m][1], vf1, Of[m][nb], 0, 0, 0);
            }
        }
        #pragma unroll
        for (int m = 0; m < 2; m++) {
            Ofs[m] = __builtin_amdgcn_mfma_f32_16x16x32_f16(pf[m][0], vones, Ofs[m], 0, 0, 0);
            Ofs[m] = __builtin_amdgcn_mfma_f32_16x16x32_f16(pf[m][1], vones, Ofs[m], 0, 0, 0);
        }
    }

    #pragma unroll
    for (int m = 0; m < 2; m++) {
        floatx4 rs;
        #pragma unroll
        for (int r = 0; r < 4; r++) rs[r] = 1.f / Ofs[m][r];
        #pragma unroll
        for (int nb = 0; nb < 4; nb++)
            #pragma unroll
            for (int r = 0; r < 4; r++) {
                int q = q0 + m * 16 + quad * 4 + r;
                int d = nb * 16 + l16;
                valh[((long)(b * SEQ + q)) * D_MODEL + h * HD + d] = (f16)(Of[m][nb][r] * rs[r]);
            }
    }
}

extern "C" void kernel_launch(void* const* d_in, const int* in_sizes, int n_in,
                              void* d_out, int out_size, void* d_ws, size_t ws_size,
                              hipStream_t stream) {
    const float* x    = (const float*)d_in[0];
    const float* mask = (const float*)d_in[1];
    const float* Wqkv = (const float*)d_in[2];
    const float* bqkv = (const float*)d_in[3];
    const float* Wout = (const float*)d_in[4];
    const float* bout = (const float*)d_in[5];
    float* out = (float*)d_out;

    char* ws = (char*)d_ws;
    f16* xh    = (f16*)(ws + 0);          // 8 MB: [4096][1024]; dead after gemm0
    f16* E     = (f16*)(ws + 0);          // 8 MB: [2048][2048] exp(mask) — overlays xh
    f16* WqkvT = (f16*)(ws + 8388608);    // 6 MB: [3072][1024]
    f16* WoutT = (f16*)(ws + 14680064);   // 2 MB: [1024][1024]
    f16* Qh    = (f16*)(ws + 16777216);   // 8 MB: [32][2048][64] (pre-scaled 1/8)
    f16* Kh    = (f16*)(ws + 25165824);   // 8 MB: [32][2048][64]
    f16* Vtg   = (f16*)(ws + 33554432);   // 8 MB: [32][64][2048] (V transposed)
    f16* valh  = (f16*)(ws + 41943040);   // 8 MB: [4096][1024]

    cvt_f32_f16<<<4096, 256, 0, stream>>>(x, xh, M_TOTAL * D_MODEL / 4);
    transpose_cvt<<<dim3(96, 32), dim3(32, 8), 0, stream>>>(Wqkv, WqkvT, 1024, 3072);
    transpose_cvt<<<dim3(32, 32), dim3(32, 8), 0, stream>>>(Wout, WoutT, 1024, 1024);
    gemm_mfma<0, 128><<<dim3(24, 32), 256, 0, stream>>>(xh, WqkvT, bqkv, Qh, Kh, Vtg, nullptr, 1024);
    exp_cvt<<<4096, 256, 0, stream>>>(mask, E, SEQ * SEQ / 4);   // xh dead now
    attn<<<dim3(16, 32), 256, 0, stream>>>(Qh, Kh, Vtg, E, valh);
    gemm_mfma<1, 64><<<dim3(16, 32), 256, 0, stream>>>(valh, WoutT, bout, nullptr, nullptr, nullptr, out, 1024);
}

// Round 6
// 243.270 us; speedup vs baseline: 1.0650x; 1.0650x over previous
//
#include <hip/hip_runtime.h>
#include <hip/hip_bf16.h>

#define D_MODEL 1024
#define NH 16
#define HD 64
#define BATCH 2
#define SEQ 2048
#define M_TOTAL (BATCH*SEQ)   // 4096

typedef _Float16 f16;
typedef _Float16 half8 __attribute__((ext_vector_type(8)));
typedef _Float16 half4v __attribute__((ext_vector_type(4)));
typedef float floatx4 __attribute__((ext_vector_type(4)));

__device__ inline void gload_lds16(const void* g, void* l) {
    __builtin_amdgcn_global_load_lds(
        (const __attribute__((address_space(1))) unsigned int*)g,
        (__attribute__((address_space(3))) unsigned int*)l, 16, 0, 0);
}

// ---------------- fp32 -> fp16 cast ----------------
__global__ void cvt_f32_f16(const float* __restrict__ src, f16* __restrict__ dst, int n4) {
    int i = blockIdx.x * blockDim.x + threadIdx.x;
    if (i < n4) {
        float4 v = ((const float4*)src)[i];
        half4v o = { (f16)v.x, (f16)v.y, (f16)v.z, (f16)v.w };
        *(half4v*)(dst + (long)i * 4) = o;
    }
}

// ---------------- E = exp(mask) in f16 ----------------
__global__ void exp_cvt(const float* __restrict__ src, f16* __restrict__ dst, int n4) {
    int i = blockIdx.x * blockDim.x + threadIdx.x;
    if (i < n4) {
        float4 v = ((const float4*)src)[i];
        half4v o = { (f16)__expf(v.x), (f16)__expf(v.y), (f16)__expf(v.z), (f16)__expf(v.w) };
        *(half4v*)(dst + (long)i * 4) = o;
    }
}

// ---------------- fp32 [R][C] -> fp16 [C][R] transpose-cast ----------------
__global__ void transpose_cvt(const float* __restrict__ src, f16* __restrict__ dst, int R, int C) {
    __shared__ float tile[32][33];
    int tx = threadIdx.x;
    int ty = threadIdx.y;
    int c0 = blockIdx.x * 32;
    int r0 = blockIdx.y * 32;
    for (int yy = 0; yy < 32; yy += 8)
        tile[ty + yy][tx] = src[(long)(r0 + ty + yy) * C + c0 + tx];
    __syncthreads();
    for (int yy = 0; yy < 32; yy += 8)
        dst[(long)(c0 + ty + yy) * R + r0 + tx] = (f16)tile[tx][ty + yy];
}

// ---------------- 128xTN-tile fp16 MFMA GEMM, BK=64, XOR-swizzled LDS ----------------
// MODE 0 (TN=128): scatter -> Qh [bh][s][d] (x0.125), Kh [bh][s][d], Vtg [bh][d][s]
// MODE 1 (TN=64):  out[m][n] = acc + bias (fp32)
template<int MODE, int TN>
__global__ __launch_bounds__(256) void gemm_mfma(
    const f16* __restrict__ A, const f16* __restrict__ BT,
    const float* __restrict__ bias,
    f16* __restrict__ Qh, f16* __restrict__ Kh, f16* __restrict__ Vtg,
    float* __restrict__ out, int Kdim)
{
    constexpr int NF = TN / 32;
    __shared__ f16 Ah[128 * 64];
    __shared__ f16 Bh[TN * 64];
    int tid  = threadIdx.x;
    int wid  = tid >> 6;
    int lane = tid & 63;
    int quad = lane >> 4;
    int l16  = lane & 15;
    int m0 = blockIdx.y * 128;
    int n0 = blockIdx.x * TN;
    int mrow = (wid >> 1) * 64;
    int ncol = (wid & 1) * (TN / 2);
    int grow = lane >> 3;
    int gchunk = (lane & 7) ^ (grow & 7);
    int sw0 = ((quad)     ^ (l16 & 7)) * 8;
    int sw1 = ((quad + 4) ^ (l16 & 7)) * 8;

    floatx4 acc[4][NF];
    #pragma unroll
    for (int mb = 0; mb < 4; mb++)
        #pragma unroll
        for (int nb = 0; nb < NF; nb++) acc[mb][nb] = (floatx4){0.f, 0.f, 0.f, 0.f};

    const f16* Abase = A + (long)m0 * Kdim;
    const f16* Bbase = BT + (long)n0 * Kdim;

    for (int k0 = 0; k0 < Kdim; k0 += 64) {
        #pragma unroll
        for (int j = 0; j < 4; j++) {
            int r = j * 32 + wid * 8 + grow;
            gload_lds16(Abase + (long)r * Kdim + k0 + gchunk * 8, &Ah[(j * 32 + wid * 8) * 64]);
        }
        #pragma unroll
        for (int j = 0; j < TN / 32; j++) {
            int r = j * 32 + wid * 8 + grow;
            gload_lds16(Bbase + (long)r * Kdim + k0 + gchunk * 8, &Bh[(j * 32 + wid * 8) * 64]);
        }
        __syncthreads();
        #pragma unroll
        for (int h = 0; h < 2; h++) {
            int sw = h ? sw1 : sw0;
            half8 af[4];
            #pragma unroll
            for (int mb = 0; mb < 4; mb++)
                af[mb] = *(const half8*)&Ah[(mrow + mb * 16 + l16) * 64 + sw];
            #pragma unroll
            for (int nb = 0; nb < NF; nb++) {
                half8 bf = *(const half8*)&Bh[(ncol + nb * 16 + l16) * 64 + sw];
                #pragma unroll
                for (int mb = 0; mb < 4; mb++)
                    acc[mb][nb] = __builtin_amdgcn_mfma_f32_16x16x32_f16(af[mb], bf, acc[mb][nb], 0, 0, 0);
            }
        }
        __syncthreads();
    }

    #pragma unroll
    for (int nb = 0; nb < NF; nb++) {
        int n = n0 + ncol + nb * 16 + l16;
        float bv = bias[n];
        int head = 0, t = 0, d = 0;
        if (MODE == 0) { head = n / 192; int rem = n % 192; t = rem / 64; d = rem % 64; }
        #pragma unroll
        for (int mb = 0; mb < 4; mb++) {
            int mbase = m0 + mrow + mb * 16 + quad * 4;
            if (MODE == 0) {
                int b = mbase >> 11;
                int s = mbase & 2047;
                long bh = b * NH + head;
                if (t == 2) {
                    half4v pack;
                    #pragma unroll
                    for (int r = 0; r < 4; r++) pack[r] = (f16)(acc[mb][nb][r] + bv);
                    *(half4v*)&Vtg[(bh * HD + d) * SEQ + s] = pack;
                } else if (t == 0) {
                    #pragma unroll
                    for (int r = 0; r < 4; r++)
                        Qh[(bh * SEQ + s + r) * HD + d] = (f16)((acc[mb][nb][r] + bv) * 0.125f);
                } else {
                    #pragma unroll
                    for (int r = 0; r < 4; r++)
                        Kh[(bh * SEQ + s + r) * HD + d] = (f16)(acc[mb][nb][r] + bv);
                }
            } else {
                #pragma unroll
                for (int r = 0; r < 4; r++)
                    out[(long)(mbase + r) * D_MODEL + n] = acc[mb][nb][r] + bv;
            }
        }
    }
}

// ---------------- flash attention v6: P stays in registers ----------------
// grid (SEQ/128, B*H), 256 threads (4 waves x 32 q-rows). Double-buffered K/V DMA
// (one barrier/iter), cross-iter E register prefetch.
// S^T = K.Q^T (16x16x32): lane holds P[key=quad*4+r][q=l16] == B-layout of
// v_mfma_f32_16x16x16_f16 -> PV computed as O^T[d][q] = V^T x P^T with A = V^T
// b64 frags from swizzled Vt. No P LDS round-trip. Denominator = per-lane float
// partials + end shfl_xor over quad bits.
__global__ __launch_bounds__(256) void attn(
    const f16* __restrict__ Qh, const f16* __restrict__ Kh, const f16* __restrict__ Vtg,
    const f16* __restrict__ E, f16* __restrict__ valh)
{
    __shared__ f16 Kl[2][64 * 64];   // [key][d], XOR-swizzled 16B chunks
    __shared__ f16 Vt[2][64 * 64];   // [d][key], XOR-swizzled 16B chunks
    int tid  = threadIdx.x;
    int wid  = tid >> 6;
    int lane = tid & 63;
    int quad = lane >> 4;
    int l16  = lane & 15;
    int bh = blockIdx.y;
    int b  = bh >> 4;
    int h  = bh & 15;
    int q0 = blockIdx.x * 128 + wid * 32;

    int grow = lane >> 3;            // 0..7
    int gpos = lane & 7;
    int l3   = l16 & 7;
    int sw0 = ((quad)     ^ l3) * 8;
    int sw1 = ((quad + 4) ^ l3) * 8;
    int qh  = quad >> 1;
    int ql4 = (quad & 1) * 4;

    const f16* Qbase = Qh + ((long)bh * SEQ + q0) * HD;
    half8 qf[2][2];
    #pragma unroll
    for (int m = 0; m < 2; m++)
        #pragma unroll
        for (int c = 0; c < 2; c++)
            qf[m][c] = *(const half8*)&Qbase[(long)(m * 16 + l16) * HD + c * 32 + quad * 8];

    floatx4 Of[2][4];
    float sums[2] = {0.f, 0.f};
    #pragma unroll
    for (int m = 0; m < 2; m++)
        #pragma unroll
        for (int nb = 0; nb < 4; nb++) Of[m][nb] = (floatx4){0.f, 0.f, 0.f, 0.f};

    const f16* Kb = Kh + (long)bh * SEQ * HD;
    const f16* Vb = Vtg + (long)bh * HD * SEQ;

    // stage tile 0 into buffer 0
    #pragma unroll
    for (int j = 0; j < 2; j++) {
        int rb = j * 32 + wid * 8;
        int row = rb + grow;
        int gk = gpos ^ (row & 7);
        gload_lds16(Kb + (long)row * HD + gk * 8, &Kl[0][rb * 64]);
        gload_lds16(Vb + (long)row * SEQ + gk * 8, &Vt[0][rb * 64]);
    }

    // E prefetch registers, parity ping-pong (statically indexed)
    half4v ef[2][2][4];
    #pragma unroll
    for (int m = 0; m < 2; m++)
        #pragma unroll
        for (int kb = 0; kb < 4; kb++)
            ef[0][m][kb] = *(const half4v*)&E[(long)(q0 + m * 16 + l16) * SEQ + kb * 16 + quad * 4];

    for (int it2 = 0; it2 < SEQ / 128; it2++) {
        #pragma unroll
        for (int p = 0; p < 2; p++) {
            int k0 = it2 * 128 + p * 64;
            __syncthreads();   // all waves done reading buf p^1; DMA(tile k0) complete

            if (k0 + 64 < SEQ) {
                int kn = k0 + 64;
                #pragma unroll
                for (int j = 0; j < 2; j++) {
                    int rb = j * 32 + wid * 8;
                    int row = rb + grow;
                    int gk = gpos ^ (row & 7);
                    gload_lds16(Kb + (long)(kn + row) * HD + gk * 8, &Kl[p ^ 1][rb * 64]);
                    gload_lds16(Vb + (long)row * SEQ + kn + gk * 8, &Vt[p ^ 1][rb * 64]);
                }
                #pragma unroll
                for (int m = 0; m < 2; m++)
                    #pragma unroll
                    for (int kb = 0; kb < 4; kb++)
                        ef[p ^ 1][m][kb] = *(const half4v*)&E[(long)(q0 + m * 16 + l16) * SEQ + kn + kb * 16 + quad * 4];
            }

            // QK^T (S^T orientation) + exp, P kept in registers
            half4v ph[2][4];
            #pragma unroll
            for (int kb = 0; kb < 4; kb++) {
                half8 kf0 = *(const half8*)&Kl[p][(kb * 16 + l16) * 64 + sw0];
                half8 kf1 = *(const half8*)&Kl[p][(kb * 16 + l16) * 64 + sw1];
                #pragma unroll
                for (int m = 0; m < 2; m++) {
                    floatx4 s = (floatx4){0.f, 0.f, 0.f, 0.f};
                    s = __builtin_amdgcn_mfma_f32_16x16x32_f16(kf0, qf[m][0], s, 0, 0, 0);
                    s = __builtin_amdgcn_mfma_f32_16x16x32_f16(kf1, qf[m][1], s, 0, 0, 0);
                    #pragma unroll
                    for (int r = 0; r < 4; r++) {
                        float pv = (float)ef[p][m][kb][r] * __expf(s[r]);
                        sums[m] += pv;
                        ph[m][kb][r] = (f16)pv;
                    }
                }
            }

            // PV: O^T += V^T x P^T via 16x16x16 MFMA, A = V^T b64 frags
            #pragma unroll
            for (int kb = 0; kb < 4; kb++) {
                int chunk = ((kb * 2 + qh) ^ l3) * 8 + ql4;
                #pragma unroll
                for (int nb = 0; nb < 4; nb++) {
                    half4v vf = *(const half4v*)&Vt[p][(nb * 16 + l16) * 64 + chunk];
                    #pragma unroll
                    for (int m = 0; m < 2; m++)
                        Of[m][nb] = __builtin_amdgcn_mfma_f32_16x16x16f16(vf, ph[m][kb], Of[m][nb], 0, 0, 0);
                }
            }
        }
    }

    // denominator: quads partition the keys -> reduce over lane bits 4,5
    #pragma unroll
    for (int m = 0; m < 2; m++) {
        float s = sums[m];
        s += __shfl_xor(s, 16);
        s += __shfl_xor(s, 32);
        sums[m] = 1.f / s;
    }

    // lane holds O[q = q0+m*16+l16][d = nb*16+quad*4+r] -> b64 stores
    #pragma unroll
    for (int m = 0; m < 2; m++) {
        long row = (long)(b * SEQ + q0 + m * 16 + l16) * D_MODEL + h * HD;
        #pragma unroll
        for (int nb = 0; nb < 4; nb++) {
            half4v o;
            #pragma unroll
            for (int r = 0; r < 4; r++) o[r] = (f16)(Of[m][nb][r] * sums[m]);
            *(half4v*)&valh[row + nb * 16 + quad * 4] = o;
        }
    }
}

extern "C" void kernel_launch(void* const* d_in, const int* in_sizes, int n_in,
                              void* d_out, int out_size, void* d_ws, size_t ws_size,
                              hipStream_t stream) {
    const float* x    = (const float*)d_in[0];
    const float* mask = (const float*)d_in[1];
    const float* Wqkv = (const float*)d_in[2];
    const float* bqkv = (const float*)d_in[3];
    const float* Wout = (const float*)d_in[4];
    const float* bout = (const float*)d_in[5];
    float* out = (float*)d_out;

    char* ws = (char*)d_ws;
    f16* xh    = (f16*)(ws + 0);          // 8 MB: [4096][1024]; dead after gemm0
    f16* E     = (f16*)(ws + 0);          // 8 MB: [2048][2048] exp(mask) — overlays xh
    f16* WqkvT = (f16*)(ws + 8388608);    // 6 MB: [3072][1024]
    f16* WoutT = (f16*)(ws + 14680064);   // 2 MB: [1024][1024]
    f16* Qh    = (f16*)(ws + 16777216);   // 8 MB: [32][2048][64] (pre-scaled 1/8)
    f16* Kh    = (f16*)(ws + 25165824);   // 8 MB: [32][2048][64]
    f16* Vtg   = (f16*)(ws + 33554432);   // 8 MB: [32][64][2048] (V transposed)
    f16* valh  = (f16*)(ws + 41943040);   // 8 MB: [4096][1024]

    cvt_f32_f16<<<4096, 256, 0, stream>>>(x, xh, M_TOTAL * D_MODEL / 4);
    transpose_cvt<<<dim3(96, 32), dim3(32, 8), 0, stream>>>(Wqkv, WqkvT, 1024, 3072);
    transpose_cvt<<<dim3(32, 32), dim3(32, 8), 0, stream>>>(Wout, WoutT, 1024, 1024);
    gemm_mfma<0, 128><<<dim3(24, 32), 256, 0, stream>>>(xh, WqkvT, bqkv, Qh, Kh, Vtg, nullptr, 1024);
    exp_cvt<<<4096, 256, 0, stream>>>(mask, E, SEQ * SEQ / 4);   // xh dead now
    attn<<<dim3(16, 32), 256, 0, stream>>>(Qh, Kh, Vtg, E, valh);
    gemm_mfma<1, 64><<<dim3(16, 32), 256, 0, stream>>>(valh, WoutT, bout, nullptr, nullptr, nullptr, out, 1024);
}